// Round 9
// baseline (2176.147 us; speedup 1.0000x reference)
//
#include <hip/hip_runtime.h>
#include <math.h>

// BayesianCTC on MI355X — round 20 (= R19 resubmitted; "container failed
// twice" matches the R16->R17 infra-flake precedent where identical source
// then passed. Audited: barrier counts wave-uniform (1+101 per wave, no
// barriers inside divergent bodies); stage() indices bounded (r<=1599,
// 4*lane<=200, em<=26.6KB); double-buffer race-free (scan reads em[k&1],
// producers write em[(k&1)^1], barrier separates reuse).
// R19 theory: the 4-wave per-step barrier round trip (~1335cy/step) is
// structural (R14-R18); TLP can't shorten a serial chain (R13); R12's
// zero-barrier register scan is correct but was starved by global-latency
// emission loads. PRODUCER-CONSUMER fixes the feed: wave 0 = R12 register
// scan (8 states/lane, shuffle halo, no per-step barriers); waves 1-3 stage
// emission rows global->LDS in 16-row double-buffered chunks; one light
// barrier per 16 steps. Math verbatim R12/R14; only u* stored.

#define Bn    16
#define Tn    1600
#define NE    512
#define OD    2048
#define Un    200
#define Sn    401
#define NLAB  201
#define NGC   256
#define LPS   256              // lpl row stride (floats)
#define CH    16               // emission rows per chunk
#define NCH   100              // chunks (1600/16)
#define EMW   208              // staged row width (floats): [0..201]=eo, [204]=eb

#define NEGINF (-INFINITY)
#define LSE_SUB_CONST_F (-2000.4586715f)        // -2001 + log(e-1)

typedef short bf8_t  __attribute__((ext_vector_type(8)));
typedef float f32x4  __attribute__((ext_vector_type(4)));

__device__ __forceinline__ unsigned short f2bf(float x) {
    unsigned int u = __float_as_uint(x);
    unsigned int r = (u + 0x7FFFu + ((u >> 16) & 1u)) >> 16;  // RNE
    return (unsigned short)r;
}
__device__ __forceinline__ void lse_merge_v(float& M, float& S, float v) {
    if (v > M) { S = S * __expf(M - v) + 1.f; M = v; }
    else       { S += __expf(v - M); }
}
__device__ __forceinline__ void lse_merge_ms(float& M, float& S, float m2, float s2) {
    if (s2 > 0.f) {
        if (m2 > M) { S = S * __expf(M - m2) + s2; M = m2; }
        else        { S += s2 * __expf(m2 - M); }
    }
}

// ------------------------------------------------------------ casts -------
__global__ __launch_bounds__(256)
void cast_hs_kernel(const float* __restrict__ src, unsigned short* __restrict__ dst, int n8) {
    int i = blockIdx.x * 256 + threadIdx.x;
    if (i >= n8) return;
    const float4* s4 = (const float4*)(src + (size_t)i * 8);
    float4 a = s4[0], b = s4[1];
    uint4 o;
    o.x = f2bf(a.x) | ((unsigned)f2bf(a.y) << 16);
    o.y = f2bf(a.z) | ((unsigned)f2bf(a.w) << 16);
    o.z = f2bf(b.x) | ((unsigned)f2bf(b.y) << 16);
    o.w = f2bf(b.z) | ((unsigned)f2bf(b.w) << 16);
    *(uint4*)(dst + (size_t)i * 8) = o;
}

// --------------------------------------------------------- gather Wg ------
__global__ __launch_bounds__(64)
void gather_kernel(const float* __restrict__ W, const float* __restrict__ bias,
                   const int* __restrict__ ys, unsigned short* __restrict__ Wgb,
                   float* __restrict__ biasg)
{
    const int b = blockIdx.x, j = blockIdx.y, tid = threadIdx.x;
    int col = -1;
    if (j == 0) col = 0;
    else if (j <= Un) { int y = ys[b * Un + j - 1]; col = (y < 0) ? 0 : y; }
    unsigned short* dst = Wgb + ((size_t)b * NGC + j) * NE;
    if (col >= 0) {
        const float* srcc = W + (size_t)col * NE;
        #pragma unroll
        for (int it = 0; it < 8; ++it) dst[tid + it * 64] = f2bf(srcc[tid + it * 64]);
    } else {
        #pragma unroll
        for (int it = 0; it < 8; ++it) dst[tid + it * 64] = 0;
    }
    if (tid == 0) biasg[b * NGC + j] = (col >= 0) ? bias[col] : 0.f;
}

// ------------------------------------------------------- main MFMA GEMM ---
#define KCH  64
#define ASTR 72

__global__ __launch_bounds__(256, 2)
void gemm_main_kernel(const unsigned short* __restrict__ hsb,
                      const unsigned short* __restrict__ Wb,
                      const float* __restrict__ bias,
                      float* __restrict__ Pm, float* __restrict__ Ps)
{
    __shared__ union {
        struct { unsigned short A[128 * ASTR]; unsigned short B[128 * ASTR]; } t;
        struct { float m[128 * 33]; float s[128 * 33]; } r;
    } sh;
    const int tid  = threadIdx.x;
    const int lane = tid & 63, w = tid >> 6;
    const int mw = w & 1, nw = w >> 1;
    const int quad = lane >> 4, lc = lane & 15;
    const int row0 = blockIdx.x * 128;
    const int c0   = blockIdx.y * 128;

    f32x4 acc[4][4];
    #pragma unroll
    for (int mi = 0; mi < 4; ++mi)
        #pragma unroll
        for (int ni = 0; ni < 4; ++ni) acc[mi][ni] = (f32x4)0.f;

    for (int kc = 0; kc < NE / KCH; ++kc) {
        __syncthreads();
        #pragma unroll
        for (int i = 0; i < 4; ++i) {
            int idx = tid + i * 256;
            int r = idx >> 3, c8 = idx & 7;
            *(uint4*)&sh.t.A[r * ASTR + c8 * 8] =
                *(const uint4*)&hsb[(size_t)(row0 + r) * NE + kc * KCH + c8 * 8];
            *(uint4*)&sh.t.B[r * ASTR + c8 * 8] =
                *(const uint4*)&Wb[(size_t)(c0 + r) * NE + kc * KCH + c8 * 8];
        }
        __syncthreads();
        #pragma unroll
        for (int ks = 0; ks < 2; ++ks) {
            bf8_t af[4], bg[4];
            #pragma unroll
            for (int mi = 0; mi < 4; ++mi)
                af[mi] = *(const bf8_t*)&sh.t.A[(mw * 64 + mi * 16 + lc) * ASTR + ks * 32 + quad * 8];
            #pragma unroll
            for (int ni = 0; ni < 4; ++ni)
                bg[ni] = *(const bf8_t*)&sh.t.B[(nw * 64 + ni * 16 + lc) * ASTR + ks * 32 + quad * 8];
            #pragma unroll
            for (int mi = 0; mi < 4; ++mi)
                #pragma unroll
                for (int ni = 0; ni < 4; ++ni)
                    acc[mi][ni] = __builtin_amdgcn_mfma_f32_16x16x32_bf16(af[mi], bg[ni], acc[mi][ni], 0, 0, 0);
        }
    }
    __syncthreads();
    float bcol[4];
    #pragma unroll
    for (int ni = 0; ni < 4; ++ni) bcol[ni] = bias[c0 + nw * 64 + ni * 16 + lc];
    #pragma unroll
    for (int mi = 0; mi < 4; ++mi)
        #pragma unroll
        for (int r = 0; r < 4; ++r) {
            float M = NEGINF, S = 0.f;
            #pragma unroll
            for (int ni = 0; ni < 4; ++ni) lse_merge_v(M, S, acc[mi][ni][r] + bcol[ni]);
            int rl = mw * 64 + mi * 16 + quad * 4 + r;
            sh.r.m[rl * 33 + nw * 16 + lc] = M;
            sh.r.s[rl * 33 + nw * 16 + lc] = S;
        }
    __syncthreads();
    if (tid < 128) {
        float M = NEGINF, S = 0.f;
        #pragma unroll 4
        for (int j = 0; j < 32; ++j) lse_merge_ms(M, S, sh.r.m[tid * 33 + j], sh.r.s[tid * 33 + j]);
        Pm[(size_t)blockIdx.y * 25600 + row0 + tid] = M;
        Ps[(size_t)blockIdx.y * 25600 + row0 + tid] = S;
    }
}

// ------------------------------------------------------------ lse reduce --
__global__ __launch_bounds__(256)
void lse_reduce_kernel(const float* __restrict__ Pm, const float* __restrict__ Ps,
                       float* __restrict__ lse)
{
    int row = blockIdx.x * 256 + threadIdx.x;
    float M = NEGINF, S = 0.f;
    #pragma unroll 4
    for (int nt = 0; nt < 16; ++nt)
        lse_merge_ms(M, S, Pm[(size_t)nt * 25600 + row], Ps[(size_t)nt * 25600 + row]);
    lse[row] = M + logf(S);
}

// ------------------------------------------------------- label MFMA GEMM --
// lpbk[row] = blank col; lpl[row][u] (stride LPS=256): u=col-1 for col 1..200,
// cols 201..255 zero-filled (staged/read unconditionally downstream).
__global__ __launch_bounds__(256, 2)
void gemm_label_kernel(const unsigned short* __restrict__ hsb,
                       const unsigned short* __restrict__ Wgb,
                       const float* __restrict__ biasg, const float* __restrict__ lse,
                       float* __restrict__ lpl, float* __restrict__ lpbk)
{
    __shared__ unsigned short shA[64 * ASTR];
    __shared__ unsigned short shB[128 * ASTR];
    const int tid  = threadIdx.x;
    const int lane = tid & 63, w = tid >> 6;
    const int mw = w & 1, nw = w >> 1;
    const int quad = lane >> 4, lc = lane & 15;
    const int b  = blockIdx.x / 25, mt = blockIdx.x % 25;
    const int r0 = b * Tn + mt * 64;
    const int c0 = blockIdx.y * 128;

    f32x4 acc[2][4];
    #pragma unroll
    for (int mi = 0; mi < 2; ++mi)
        #pragma unroll
        for (int ni = 0; ni < 4; ++ni) acc[mi][ni] = (f32x4)0.f;

    const unsigned short* Wgbb = Wgb + (size_t)b * NGC * NE;
    for (int kc = 0; kc < NE / KCH; ++kc) {
        __syncthreads();
        #pragma unroll
        for (int i = 0; i < 2; ++i) {
            int idx = tid + i * 256;
            int r = idx >> 3, c8 = idx & 7;
            *(uint4*)&shA[r * ASTR + c8 * 8] =
                *(const uint4*)&hsb[(size_t)(r0 + r) * NE + kc * KCH + c8 * 8];
        }
        #pragma unroll
        for (int i = 0; i < 4; ++i) {
            int idx = tid + i * 256;
            int r = idx >> 3, c8 = idx & 7;
            *(uint4*)&shB[r * ASTR + c8 * 8] =
                *(const uint4*)&Wgbb[(size_t)(c0 + r) * NE + kc * KCH + c8 * 8];
        }
        __syncthreads();
        #pragma unroll
        for (int ks = 0; ks < 2; ++ks) {
            bf8_t af[2], bg[4];
            #pragma unroll
            for (int mi = 0; mi < 2; ++mi)
                af[mi] = *(const bf8_t*)&shA[(mw * 32 + mi * 16 + lc) * ASTR + ks * 32 + quad * 8];
            #pragma unroll
            for (int ni = 0; ni < 4; ++ni)
                bg[ni] = *(const bf8_t*)&shB[(nw * 64 + ni * 16 + lc) * ASTR + ks * 32 + quad * 8];
            #pragma unroll
            for (int mi = 0; mi < 2; ++mi)
                #pragma unroll
                for (int ni = 0; ni < 4; ++ni)
                    acc[mi][ni] = __builtin_amdgcn_mfma_f32_16x16x32_bf16(af[mi], bg[ni], acc[mi][ni], 0, 0, 0);
        }
    }
    #pragma unroll
    for (int mi = 0; mi < 2; ++mi)
        #pragma unroll
        for (int r = 0; r < 4; ++r) {
            int row = r0 + mw * 32 + mi * 16 + quad * 4 + r;
            float lsv = lse[row];
            #pragma unroll
            for (int ni = 0; ni < 4; ++ni) {
                int col = c0 + nw * 64 + ni * 16 + lc;
                float v = acc[mi][ni][r] + biasg[b * NGC + col] - lsv;
                if (col == 0)          lpbk[row] = v;
                else if (col < NLAB)   lpl[(size_t)row * LPS + (col - 1)] = v;
                else                   lpl[(size_t)row * LPS + (col - 1)] = 0.f;
            }
        }
}

// -------- K2: producer-consumer register scan (zero per-step barriers) ----
__device__ __forceinline__ float lse2f(float a, float b) {
    float mx = fmaxf(a, b);
    if (isinf(mx)) return NEGINF;
    return mx + __logf(__expf(a - mx) + __expf(b - mx));
}
__device__ __forceinline__ float lse3f(float v0, float v1, float v2) {
    float mx = fmaxf(v0, fmaxf(v1, v2));
    if (isinf(mx)) return NEGINF;
    return mx + __logf(__expf(v0 - mx) + __expf(v1 - mx) + __expf(v2 - mx));
}

// LDS-only barrier: ds ops ordered, global loads stay in flight.
#define STEP_BAR() do { \
    asm volatile("s_waitcnt lgkmcnt(0)" ::: "memory"); \
    __builtin_amdgcn_s_barrier(); \
    __builtin_amdgcn_sched_barrier(0); \
} while (0)

__global__ __launch_bounds__(256)
void scan_kernel(const float* __restrict__ lpl, const float* __restrict__ lpbk,
                 const int* __restrict__ hlens, const int* __restrict__ ys,
                 float* __restrict__ ast, float* __restrict__ bst)
{
    __shared__ float em[2][CH][EMW];     // 26.6 KB staged emissions
    __shared__ int   sh_olen, sh_hlen;

    const int tid  = threadIdx.x;
    const int wid  = tid >> 6, lane = tid & 63;
    const int b    = blockIdx.x & (Bn - 1);
    const int role = blockIdx.x >> 4;    // 0 = alpha, 1 = beta

    if (tid == 0) {
        int o = 0;
        for (int u = 0; u < Un; u++) if (ys[b * Un + u] >= 0) o++;
        sh_olen = o;
        sh_hlen = hlens[b];
    }
    __syncthreads();
    const int olen = sh_olen, hlen = sh_hlen, ustar = olen - 1;

    const float* lplb = lpl + (size_t)b * Tn * LPS;
    const float* lpbb = lpbk + (size_t)b * Tn;

    // ------------- scan-wave per-lane invariants (wave 0 only uses them) ---
    const int u0 = 4 * lane;             // first label index owned
    const int s0 = 8 * lane;             // first CTC state owned
    bool al[5];                          // allow for odd state of u = u0+j
    #pragma unroll
    for (int j = 0; j < 5; ++j) {
        int u = u0 + j;
        bool a = false;
        if (u >= 1 && u < Un) {
            int y0 = ys[b * Un + u - 1]; if (y0 < 0) y0 = 0;
            int y1 = ys[b * Un + u];     if (y1 < 0) y1 = 0;
            a = (y0 != y1);
        }
        al[j] = a;
    }
    bool vm[8];
    #pragma unroll
    for (int j = 0; j < 8; ++j) vm[j] = (s0 + j < Sn);

    float st[8];
    #pragma unroll
    for (int j = 0; j < 8; ++j) st[j] = NEGINF;

    float* as = ast + (size_t)b * Tn;
    float* bs = bst + (size_t)b * Tn;
    if (role == 0 && wid == 0) {
        if (lane == 0) {
            st[0] = lpbb[0];
            st[1] = lplb[0];
            as[0] = (ustar == 0) ? lplb[0] : NEGINF;
        }
    }
    const int eoff = (lane < 50) ? 4 * lane : 196;       // clamped float4 base
    const int eoff4 = (4 * lane + 4 < 200) ? 4 * lane + 4 : 200;  // e1 extra

    // ---------------------- producer staging lambda ------------------------
    // chunk k, exec index j = 16k+i; emission row:
    //   alpha: r = j+1 (clamp 1599)   beta: r = min(1600-j, 1599)
    auto stage = [&](int k, int buf) {
        for (int i = wid - 1; i < CH; i += 3) {
            int j = CH * k + i;
            int r = role ? (1600 - j) : (j + 1);
            if (r > Tn - 1) r = Tn - 1;
            if (r < 0) r = 0;
            if (lane < 51) {
                float4 v = *(const float4*)&lplb[(size_t)r * LPS + 4 * lane];
                *(float4*)&em[buf][i][4 * lane] = v;
            } else if (lane == 51) {
                em[buf][i][204] = lpbb[r];
            }
        }
    };

    // prologue: stage chunk 0
    if (wid > 0) stage(0, 0);
    STEP_BAR();

    for (int k = 0; k < NCH; ++k) {
        const int cb = k & 1;
        if (wid > 0) {
            if (k + 1 < NCH) stage(k + 1, cb ^ 1);
        } else if (role == 0) {
            // ---------------- alpha: 16 steps, no barriers ----------------
            #pragma unroll 4
            for (int i = 0; i < CH; ++i) {
                const int j = CH * k + i;
                if (j >= Tn - 1) break;            // 1599 steps total
                const int t = j + 1;
                float4 eo = *(const float4*)&em[cb][i][eoff];
                float  eb = em[cb][i][204];
                float p1 = __shfl_up(st[7], 1);
                if (lane == 0) p1 = NEGINF;
                float ns[8];
                #pragma unroll
                for (int q = 0; q < 4; ++q) {
                    float cm1 = (q == 0) ? p1 : st[2 * q - 1];
                    float c2  = st[2 * q], c3 = st[2 * q + 1];
                    float nv0 = lse2f(c2, cm1);
                    if (!isinf(nv0)) nv0 += eb;
                    float a1v2 = al[q] ? cm1 : NEGINF;
                    float nv1 = lse3f(c3, c2, a1v2);
                    float eoq = (q == 0) ? eo.x : (q == 1) ? eo.y : (q == 2) ? eo.z : eo.w;
                    if (!isinf(nv1)) nv1 += eoq;
                    ns[2 * q]     = vm[2 * q]     ? nv0 : NEGINF;
                    ns[2 * q + 1] = vm[2 * q + 1] ? nv1 : NEGINF;
                    if (u0 + q == ustar) as[t] = ns[2 * q + 1];
                }
                #pragma unroll
                for (int jj = 0; jj < 8; ++jj) st[jj] = ns[jj];
            }
        } else {
            // ---------------- beta: 16 steps, no barriers -----------------
            #pragma unroll 4
            for (int i = 0; i < CH; ++i) {
                const int j = CH * k + i;
                const int T = Tn - 1 - j;
                float4 eo  = *(const float4*)&em[cb][i][eoff];
                float  eo4 = em[cb][i][eoff4];
                float  eb  = em[cb][i][204];
                float n1 = __shfl_down(st[0], 1);
                float n2 = __shfl_down(st[1], 1);
                if (lane == 63) { n1 = NEGINF; n2 = NEGINF; }
                float ns[8];
                #pragma unroll
                for (int q = 0; q < 4; ++q) {
                    const int se = s0 + 2 * q;
                    const int u  = u0 + q;
                    float c0 = st[2 * q],     c1 = st[2 * q + 1];
                    float c2 = (q < 3) ? st[2 * q + 2] : n1;
                    float c3 = (q < 3) ? st[2 * q + 3] : n2;
                    float e0 = (q == 0) ? eo.x : (q == 1) ? eo.y : (q == 2) ? eo.z : eo.w;
                    float e1 = (q == 0) ? eo.y : (q == 1) ? eo.z : (q == 2) ? eo.w : eo4;
                    float g0e = eb + c0;
                    float g1e = e0 + c1;
                    float nv0 = lse2f(g0e, g1e);
                    float g0o = e0 + c1;
                    float g1o = eb + c2;
                    float g2o = al[q + 1] ? (e1 + c3) : NEGINF;
                    float mh = fmaxf(g1o, g2o);
                    float h = NEGINF;
                    if (!isinf(mh))
                        h = mh + __logf(__expf(g1o - mh) + __expf(g2o - mh));
                    float nv1 = lse3f(g0o, g1o, g2o);
                    if (T == hlen - 1) {
                        nv0 = (se == 2 * olen || se == 2 * olen - 1) ? 0.f : NEGINF;
                        nv1 = (se + 1 == 2 * olen || se + 1 == 2 * olen - 1) ? 0.f : NEGINF;
                    }
                    ns[2 * q]     = vm[2 * q]     ? nv0 : NEGINF;
                    ns[2 * q + 1] = vm[2 * q + 1] ? nv1 : NEGINF;
                    if (u == ustar) {
                        float bp;
                        if (T >= hlen)           bp = NEGINF;
                        else if (T == hlen - 1)  bp = 0.f;        // u == olen-1
                        else if (isinf(g0o))     bp = h;
                        else if (isinf(h))       bp = LSE_SUB_CONST_F;
                        else {
                            float sumlog = h - g0o;
                            int kk = (int)((__float_as_uint(fabsf(g0o)) >> 23) & 0xFF) - 127 - 53;
                            if (kk < -53) kk = -53;
                            bp = (sumlog > 709.7827f || sumlog < 0.69314718f * (float)kk)
                                 ? LSE_SUB_CONST_F : h;
                        }
                        bs[T] = bp;
                    }
                }
                #pragma unroll
                for (int jj = 0; jj < 8; ++jj) st[jj] = ns[jj];
            }
        }
        STEP_BAR();
    }
}

// --------------------- K3: loss at u* only --------------------------------
#define TCH 8
#define TPC (Tn / TCH)

__global__ __launch_bounds__(64)
void loss_kernel(const int* __restrict__ hlens, const int* __restrict__ ys,
                 const float* __restrict__ ast, const float* __restrict__ bst,
                 float* __restrict__ lossb)
{
    const int b = blockIdx.x, tid = threadIdx.x;
    __shared__ float sm[TCH], ss[TCH];
    __shared__ int sh_olen;
    if (tid == 0) {
        int o = 0;
        for (int u = 0; u < Un; u++) if (ys[b * Un + u] >= 0) o++;
        sh_olen = o;
    }
    __syncthreads();
    const int hlen = hlens[b];
    const float risk_c = 0.1f / (float)hlen;
    if (tid < TCH) {
        float m = NEGINF, s = 0.f;
        const float* as = ast + (size_t)b * Tn;
        const float* bs = bst + (size_t)b * Tn;
        const int t0 = tid * TPC, t1 = t0 + TPC;
        for (int t = t0; t < t1; ++t) {
            float v = as[t] + bs[t] + (float)(t + 1) * risk_c;
            if (!isinf(v)) lse_merge_v(m, s, v);
        }
        sm[tid] = m; ss[tid] = s;
    }
    __syncthreads();
    if (tid == 0) {
        float M = NEGINF, S = 0.f;
        #pragma unroll
        for (int c = 0; c < TCH; ++c) lse_merge_ms(M, S, sm[c], ss[c]);
        float lf = (S == 0.f) ? NEGINF : M + __logf(S);
        if (hlen < sh_olen) lf = 0.f;
        lossb[b] = lf;
    }
}

// ---------------------------------------------------------------- K4 ------
__global__ void finalize_kernel(const float* __restrict__ lossb, float* __restrict__ out) {
    if (threadIdx.x == 0 && blockIdx.x == 0) {
        float ssum = 0.f;
        for (int i = 0; i < Bn; i++) ssum += lossb[i];
        out[0] = -ssum / (float)Bn;
    }
}

// ------------------------------------------------------------- launch -----
extern "C" void kernel_launch(void* const* d_in, const int* in_sizes, int n_in,
                              void* d_out, int out_size, void* d_ws, size_t ws_size,
                              hipStream_t stream) {
    const float* hs    = (const float*)d_in[0];
    const float* W     = (const float*)d_in[1];
    const float* bias  = (const float*)d_in[2];
    const int*   hlens = (const int*)d_in[3];
    const int*   ys    = (const int*)d_in[4];
    float* out = (float*)d_out;

    // ---- workspace (~63 MB) ----
    char* p = (char*)d_ws;
    float* lpl    = (float*)p;  p += (size_t)25601 * LPS * 4;         // 26.2 MB (stride 256, +1 pad row)
    float* lpbk   = (float*)p;  p += (size_t)25600 * 4;               // 0.10 MB
    unsigned short* hsb = (unsigned short*)p; p += (size_t)25600 * NE * 2;    // 26.2 MB
    unsigned short* Wb  = (unsigned short*)p; p += (size_t)OD * NE * 2;       // 2.1 MB
    unsigned short* Wgb = (unsigned short*)p; p += (size_t)Bn * NGC * NE * 2; // 4.2 MB
    float* Pm    = (float*)p;   p += (size_t)16 * 25600 * 4;          // 1.64 MB
    float* Ps    = (float*)p;   p += (size_t)16 * 25600 * 4;          // 1.64 MB
    float* lse   = (float*)p;   p += (size_t)25600 * 4;               // 0.10 MB
    float* biasg = (float*)p;   p += (size_t)Bn * NGC * 4;            // 16 KB
    float* ast   = (float*)p;   p += (size_t)Bn * Tn * 4;             // 0.10 MB
    float* bst   = (float*)p;   p += (size_t)Bn * Tn * 4;             // 0.10 MB
    float* lossb = (float*)p;   p += 256;

    hipLaunchKernelGGL(cast_hs_kernel, dim3(6400), dim3(256), 0, stream,
                       hs, hsb, 25600 * NE / 8);
    hipLaunchKernelGGL(cast_hs_kernel, dim3(512), dim3(256), 0, stream,
                       W, Wb, OD * NE / 8);
    hipLaunchKernelGGL(gather_kernel, dim3(Bn, NGC), dim3(64), 0, stream,
                       W, bias, ys, Wgb, biasg);
    hipLaunchKernelGGL(gemm_main_kernel, dim3(200, 16), dim3(256), 0, stream,
                       hsb, Wb, bias, Pm, Ps);
    hipLaunchKernelGGL(lse_reduce_kernel, dim3(100), dim3(256), 0, stream,
                       Pm, Ps, lse);
    hipLaunchKernelGGL(gemm_label_kernel, dim3(400, 2), dim3(256), 0, stream,
                       hsb, Wgb, biasg, lse, lpl, lpbk);
    hipLaunchKernelGGL(scan_kernel, dim3(2 * Bn), dim3(256), 0, stream,
                       lpl, lpbk, hlens, ys, ast, bst);
    hipLaunchKernelGGL(loss_kernel, dim3(Bn), dim3(64), 0, stream,
                       hlens, ys, ast, bst, lossb);
    hipLaunchKernelGGL(finalize_kernel, dim3(1), dim3(64), 0, stream, lossb, out);
}

// Round 10
// 1227.936 us; speedup vs baseline: 1.7722x; 1.7722x over previous
//
#include <hip/hip_runtime.h>
#include <math.h>

// BayesianCTC on MI355X — round 21.
// R19/R20 post-mortem: producer-consumer failed (1850us): 8-states/lane
// single-wave scan is intrinsically ~2700cy/step (4x per-step issue on one
// SIMD, unhidden) vs 1335 for 4-wave/2-state+barrier. Good regime = 4 waves
// x 2 states/thread; remaining cost = per-step s_barrier.
// R21: OVERLAPPING-HALO WINDOWS remove the barrier from the chain while
// keeping R18's exact math. Influence speed is 2 states/step (alpha reads
// s-2..s, beta reads s..s+2). Each wave owns a private 126-slot segment:
// 102-state core (even-aligned) + 24-state one-sided halo (alpha: below;
// beta: above), 63 threads x 2 states. Within a K=12 window: wave-synchronous
// steps, per-step sync = lgkmcnt(0)+sched_barrier(0) ONLY (no s_barrier);
// halo slots stale at 2/step -> core exact for <=12 steps (tight).
// Every 12 steps: light barrier -> copy 24 halo values from neighbor's core
// -> light barrier. Barriers 1600->268. Halo redundancy ~24% arith.
// Math verbatim R18 (lse ordering, classifier, resets, u*-only stores);
// u* store guarded by core-membership (halo copy of u* is stale).

#define Bn    16
#define Tn    1600
#define NE    512
#define OD    2048
#define Un    200
#define Sn    401
#define NLAB  201
#define NGC   256
#define LPS   256              // lpl row stride (floats)
#define KW    12               // steps per halo window

#define NEGINF (-INFINITY)
#define LSE_SUB_CONST_F (-2000.4586715f)        // -2001 + log(e-1)

typedef short bf8_t  __attribute__((ext_vector_type(8)));
typedef float f32x4  __attribute__((ext_vector_type(4)));

__device__ __forceinline__ unsigned short f2bf(float x) {
    unsigned int u = __float_as_uint(x);
    unsigned int r = (u + 0x7FFFu + ((u >> 16) & 1u)) >> 16;  // RNE
    return (unsigned short)r;
}
__device__ __forceinline__ void lse_merge_v(float& M, float& S, float v) {
    if (v > M) { S = S * __expf(M - v) + 1.f; M = v; }
    else       { S += __expf(v - M); }
}
__device__ __forceinline__ void lse_merge_ms(float& M, float& S, float m2, float s2) {
    if (s2 > 0.f) {
        if (m2 > M) { S = S * __expf(M - m2) + s2; M = m2; }
        else        { S += s2 * __expf(m2 - M); }
    }
}

// ------------------------------------------------------------ casts -------
__global__ __launch_bounds__(256)
void cast_hs_kernel(const float* __restrict__ src, unsigned short* __restrict__ dst, int n8) {
    int i = blockIdx.x * 256 + threadIdx.x;
    if (i >= n8) return;
    const float4* s4 = (const float4*)(src + (size_t)i * 8);
    float4 a = s4[0], b = s4[1];
    uint4 o;
    o.x = f2bf(a.x) | ((unsigned)f2bf(a.y) << 16);
    o.y = f2bf(a.z) | ((unsigned)f2bf(a.w) << 16);
    o.z = f2bf(b.x) | ((unsigned)f2bf(b.y) << 16);
    o.w = f2bf(b.z) | ((unsigned)f2bf(b.w) << 16);
    *(uint4*)(dst + (size_t)i * 8) = o;
}

// --------------------------------------------------------- gather Wg ------
__global__ __launch_bounds__(64)
void gather_kernel(const float* __restrict__ W, const float* __restrict__ bias,
                   const int* __restrict__ ys, unsigned short* __restrict__ Wgb,
                   float* __restrict__ biasg)
{
    const int b = blockIdx.x, j = blockIdx.y, tid = threadIdx.x;
    int col = -1;
    if (j == 0) col = 0;
    else if (j <= Un) { int y = ys[b * Un + j - 1]; col = (y < 0) ? 0 : y; }
    unsigned short* dst = Wgb + ((size_t)b * NGC + j) * NE;
    if (col >= 0) {
        const float* srcc = W + (size_t)col * NE;
        #pragma unroll
        for (int it = 0; it < 8; ++it) dst[tid + it * 64] = f2bf(srcc[tid + it * 64]);
    } else {
        #pragma unroll
        for (int it = 0; it < 8; ++it) dst[tid + it * 64] = 0;
    }
    if (tid == 0) biasg[b * NGC + j] = (col >= 0) ? bias[col] : 0.f;
}

// ------------------------------------------------------- main MFMA GEMM ---
#define KCH  64
#define ASTR 72

__global__ __launch_bounds__(256, 2)
void gemm_main_kernel(const unsigned short* __restrict__ hsb,
                      const unsigned short* __restrict__ Wb,
                      const float* __restrict__ bias,
                      float* __restrict__ Pm, float* __restrict__ Ps)
{
    __shared__ union {
        struct { unsigned short A[128 * ASTR]; unsigned short B[128 * ASTR]; } t;
        struct { float m[128 * 33]; float s[128 * 33]; } r;
    } sh;
    const int tid  = threadIdx.x;
    const int lane = tid & 63, w = tid >> 6;
    const int mw = w & 1, nw = w >> 1;
    const int quad = lane >> 4, lc = lane & 15;
    const int row0 = blockIdx.x * 128;
    const int c0   = blockIdx.y * 128;

    f32x4 acc[4][4];
    #pragma unroll
    for (int mi = 0; mi < 4; ++mi)
        #pragma unroll
        for (int ni = 0; ni < 4; ++ni) acc[mi][ni] = (f32x4)0.f;

    for (int kc = 0; kc < NE / KCH; ++kc) {
        __syncthreads();
        #pragma unroll
        for (int i = 0; i < 4; ++i) {
            int idx = tid + i * 256;
            int r = idx >> 3, c8 = idx & 7;
            *(uint4*)&sh.t.A[r * ASTR + c8 * 8] =
                *(const uint4*)&hsb[(size_t)(row0 + r) * NE + kc * KCH + c8 * 8];
            *(uint4*)&sh.t.B[r * ASTR + c8 * 8] =
                *(const uint4*)&Wb[(size_t)(c0 + r) * NE + kc * KCH + c8 * 8];
        }
        __syncthreads();
        #pragma unroll
        for (int ks = 0; ks < 2; ++ks) {
            bf8_t af[4], bg[4];
            #pragma unroll
            for (int mi = 0; mi < 4; ++mi)
                af[mi] = *(const bf8_t*)&sh.t.A[(mw * 64 + mi * 16 + lc) * ASTR + ks * 32 + quad * 8];
            #pragma unroll
            for (int ni = 0; ni < 4; ++ni)
                bg[ni] = *(const bf8_t*)&sh.t.B[(nw * 64 + ni * 16 + lc) * ASTR + ks * 32 + quad * 8];
            #pragma unroll
            for (int mi = 0; mi < 4; ++mi)
                #pragma unroll
                for (int ni = 0; ni < 4; ++ni)
                    acc[mi][ni] = __builtin_amdgcn_mfma_f32_16x16x32_bf16(af[mi], bg[ni], acc[mi][ni], 0, 0, 0);
        }
    }
    __syncthreads();
    float bcol[4];
    #pragma unroll
    for (int ni = 0; ni < 4; ++ni) bcol[ni] = bias[c0 + nw * 64 + ni * 16 + lc];
    #pragma unroll
    for (int mi = 0; mi < 4; ++mi)
        #pragma unroll
        for (int r = 0; r < 4; ++r) {
            float M = NEGINF, S = 0.f;
            #pragma unroll
            for (int ni = 0; ni < 4; ++ni) lse_merge_v(M, S, acc[mi][ni][r] + bcol[ni]);
            int rl = mw * 64 + mi * 16 + quad * 4 + r;
            sh.r.m[rl * 33 + nw * 16 + lc] = M;
            sh.r.s[rl * 33 + nw * 16 + lc] = S;
        }
    __syncthreads();
    if (tid < 128) {
        float M = NEGINF, S = 0.f;
        #pragma unroll 4
        for (int j = 0; j < 32; ++j) lse_merge_ms(M, S, sh.r.m[tid * 33 + j], sh.r.s[tid * 33 + j]);
        Pm[(size_t)blockIdx.y * 25600 + row0 + tid] = M;
        Ps[(size_t)blockIdx.y * 25600 + row0 + tid] = S;
    }
}

// ------------------------------------------------------------ lse reduce --
__global__ __launch_bounds__(256)
void lse_reduce_kernel(const float* __restrict__ Pm, const float* __restrict__ Ps,
                       float* __restrict__ lse)
{
    int row = blockIdx.x * 256 + threadIdx.x;
    float M = NEGINF, S = 0.f;
    #pragma unroll 4
    for (int nt = 0; nt < 16; ++nt)
        lse_merge_ms(M, S, Pm[(size_t)nt * 25600 + row], Ps[(size_t)nt * 25600 + row]);
    lse[row] = M + logf(S);
}

// ------------------------------------------------------- label MFMA GEMM --
// lpbk[row] = blank col; lpl[row][u] (stride LPS=256): u=col-1 for col 1..200,
// cols 201..255 zero-filled (read unconditionally downstream).
__global__ __launch_bounds__(256, 2)
void gemm_label_kernel(const unsigned short* __restrict__ hsb,
                       const unsigned short* __restrict__ Wgb,
                       const float* __restrict__ biasg, const float* __restrict__ lse,
                       float* __restrict__ lpl, float* __restrict__ lpbk)
{
    __shared__ unsigned short shA[64 * ASTR];
    __shared__ unsigned short shB[128 * ASTR];
    const int tid  = threadIdx.x;
    const int lane = tid & 63, w = tid >> 6;
    const int mw = w & 1, nw = w >> 1;
    const int quad = lane >> 4, lc = lane & 15;
    const int b  = blockIdx.x / 25, mt = blockIdx.x % 25;
    const int r0 = b * Tn + mt * 64;
    const int c0 = blockIdx.y * 128;

    f32x4 acc[2][4];
    #pragma unroll
    for (int mi = 0; mi < 2; ++mi)
        #pragma unroll
        for (int ni = 0; ni < 4; ++ni) acc[mi][ni] = (f32x4)0.f;

    const unsigned short* Wgbb = Wgb + (size_t)b * NGC * NE;
    for (int kc = 0; kc < NE / KCH; ++kc) {
        __syncthreads();
        #pragma unroll
        for (int i = 0; i < 2; ++i) {
            int idx = tid + i * 256;
            int r = idx >> 3, c8 = idx & 7;
            *(uint4*)&shA[r * ASTR + c8 * 8] =
                *(const uint4*)&hsb[(size_t)(r0 + r) * NE + kc * KCH + c8 * 8];
        }
        #pragma unroll
        for (int i = 0; i < 4; ++i) {
            int idx = tid + i * 256;
            int r = idx >> 3, c8 = idx & 7;
            *(uint4*)&shB[r * ASTR + c8 * 8] =
                *(const uint4*)&Wgbb[(size_t)(c0 + r) * NE + kc * KCH + c8 * 8];
        }
        __syncthreads();
        #pragma unroll
        for (int ks = 0; ks < 2; ++ks) {
            bf8_t af[2], bg[4];
            #pragma unroll
            for (int mi = 0; mi < 2; ++mi)
                af[mi] = *(const bf8_t*)&shA[(mw * 32 + mi * 16 + lc) * ASTR + ks * 32 + quad * 8];
            #pragma unroll
            for (int ni = 0; ni < 4; ++ni)
                bg[ni] = *(const bf8_t*)&shB[(nw * 64 + ni * 16 + lc) * ASTR + ks * 32 + quad * 8];
            #pragma unroll
            for (int mi = 0; mi < 2; ++mi)
                #pragma unroll
                for (int ni = 0; ni < 4; ++ni)
                    acc[mi][ni] = __builtin_amdgcn_mfma_f32_16x16x32_bf16(af[mi], bg[ni], acc[mi][ni], 0, 0, 0);
        }
    }
    #pragma unroll
    for (int mi = 0; mi < 2; ++mi)
        #pragma unroll
        for (int r = 0; r < 4; ++r) {
            int row = r0 + mw * 32 + mi * 16 + quad * 4 + r;
            float lsv = lse[row];
            #pragma unroll
            for (int ni = 0; ni < 4; ++ni) {
                int col = c0 + nw * 64 + ni * 16 + lc;
                float v = acc[mi][ni][r] + biasg[b * NGC + col] - lsv;
                if (col == 0)          lpbk[row] = v;
                else if (col < NLAB)   lpl[(size_t)row * LPS + (col - 1)] = v;
                else                   lpl[(size_t)row * LPS + (col - 1)] = 0.f;
            }
        }
}

// ---------------- K2: halo-windowed 4-wave scan (no per-step barrier) -----
__device__ __forceinline__ float lse2f(float a, float b) {
    float mx = fmaxf(a, b);
    if (isinf(mx)) return NEGINF;
    return mx + __logf(__expf(a - mx) + __expf(b - mx));
}
__device__ __forceinline__ float lse3f(float v0, float v1, float v2) {
    float mx = fmaxf(v0, fmaxf(v1, v2));
    if (isinf(mx)) return NEGINF;
    return mx + __logf(__expf(v0 - mx) + __expf(v1 - mx) + __expf(v2 - mx));
}

// per-step intra-wave LDS ordering (no barrier)
#define LGKM_FENCE() do { \
    asm volatile("s_waitcnt lgkmcnt(0)" ::: "memory"); \
    __builtin_amdgcn_sched_barrier(0); \
} while (0)
// light block barrier: LDS ordered, global loads stay in flight
#define LBAR() do { \
    asm volatile("s_waitcnt lgkmcnt(0)" ::: "memory"); \
    __builtin_amdgcn_s_barrier(); \
    __builtin_amdgcn_sched_barrier(0); \
} while (0)

__global__ __launch_bounds__(256)
void scan_kernel(const float* __restrict__ lpl, const float* __restrict__ lpbk,
                 const int* __restrict__ hlens, const int* __restrict__ ys,
                 float* __restrict__ ast, float* __restrict__ bst)
{
    // buf[plane][wave][slot]: per-wave private 128-float segment.
    // alpha: slots arr[2..127] = local states l=0..125, g = 102*w - 24 + l
    //        (l 0..23 = lower halo, 24..125 = core); arr[0..1] = NEGINF pads.
    // beta:  arr[0..125] = l, g = 102*w + l (l 0..101 core, 102..125 halo);
    //        arr[126..127] = NEGINF pads.
    __shared__ float buf[2][4][128];
    __shared__ float ebs[Tn];
    __shared__ int   sh_olen, sh_hlen;

    const int tid  = threadIdx.x;
    const int wid  = tid >> 6, lane = tid & 63;
    const int b    = blockIdx.x & (Bn - 1);
    const int role = blockIdx.x >> 4;

    if (tid == 0) {
        int o = 0;
        for (int u = 0; u < Un; u++) if (ys[b * Un + u] >= 0) o++;
        sh_olen = o;
        sh_hlen = hlens[b];
    }
    {
        float* bp0 = &buf[0][0][0];
        for (int i = tid; i < 2 * 4 * 128; i += 256) bp0[i] = NEGINF;
    }
    const float* lpbb = lpbk + (size_t)b * Tn;
    for (int i = tid; i < Tn; i += 256) ebs[i] = lpbb[i];
    __syncthreads();

    const int olen = sh_olen, hlen = sh_hlen;
    const int gstar = 2 * olen - 1;            // odd state of u* = olen-1
    const float* lplb = lpl + (size_t)b * Tn * LPS;
    const bool act = (lane < 63);

    if (role == 0) {
        // =========================== alpha ===========================
        float* as = ast + (size_t)b * Tn;
        // initial state (t=0): state0 = lpbk[0], state1 = lpl[0][0]
        if (wid == 0 && lane == 12) {           // g0 = 0 -> slots l=24,25
            buf[0][0][26] = lpbb[0];
            buf[0][0][27] = lplb[0];
        }
        if (tid == 0 && olen >= 1) as[0] = (olen == 1) ? lplb[0] : NEGINF;

        const int g0 = 102 * wid - 24 + 2 * lane;   // even global state
        const int g1 = g0 + 1;
        const bool v0 = act && g0 >= 0 && g0 <= 400;
        const bool v1 = act && g1 >= 1 && g1 <= 400;
        const int uo = g0 >> 1;                 // label idx of odd state (may be <0)
        bool allow = false;
        if (uo >= 1 && uo < Un) {
            int y0 = ys[b * Un + uo - 1]; if (y0 < 0) y0 = 0;
            int y1 = ys[b * Un + uo];     if (y1 < 0) y1 = 0;
            allow = (y0 != y1);
        }
        int c = uo; if (c < 0) c = 0; if (c > 255) c = 255;
        const bool isstar = v1 && (lane >= 12) && (g1 == gstar);   // core-only

        float eoA = lplb[(size_t)1 * LPS + c];  // emission row t
        float eoB = lplb[(size_t)2 * LPS + c];  // emission row t+1
        int t = 1;
        for (int win = 0; win < 134; ++win) {
            LBAR();
            if (wid > 0 && lane < 24)            // halo <- neighbor core
                buf[0][wid][2 + lane] = buf[0][wid - 1][104 + lane];
            LBAR();
            for (int j = 0; j < KW; ++j) {
                if (t >= Tn) break;              // block-uniform
                const float* cur = &buf[(t - 1) & 1][wid][0];
                float* nxt = &buf[t & 1][wid][0];
                int nrow = t + 2; if (nrow > Tn - 1) nrow = Tn - 1;
                float eoN = lplb[(size_t)nrow * LPS + c];
                float ebt = ebs[t];
                if (act) {
                    float c1 = cur[2 * lane + 1];
                    float c2 = cur[2 * lane + 2];
                    float c3 = cur[2 * lane + 3];
                    float nv0 = lse2f(c2, c1) + ebt;
                    float a1v2 = allow ? c1 : NEGINF;
                    float nv1 = lse3f(c3, c2, a1v2) + eoA;
                    nxt[2 * lane + 2] = v0 ? nv0 : NEGINF;
                    nxt[2 * lane + 3] = v1 ? nv1 : NEGINF;
                    if (isstar) as[t] = nv1;
                }
                LGKM_FENCE();
                eoA = eoB; eoB = eoN;
                ++t;
            }
        }
    } else {
        // ============================ beta ===========================
        float* bs = bst + (size_t)b * Tn;
        const int g0 = 102 * wid + 2 * lane;    // even global state
        const int g1 = g0 + 1;
        const bool v0 = act && g0 <= 400;
        const bool v1 = act && g1 <= 400;
        const int u0 = g0 >> 1;                 // = 51*wid + lane
        bool a2 = false;                        // allow for odd state g1+2
        if (u0 + 1 >= 1 && u0 + 1 < Un) {
            int y0 = ys[b * Un + u0];     if (y0 < 0) y0 = 0;
            int y1 = ys[b * Un + u0 + 1]; if (y1 < 0) y1 = 0;
            a2 = (y0 != y1);
        }
        int c0 = u0; if (c0 > 254) c0 = 254;
        const bool isstar = v1 && (lane <= 50) && (g1 == gstar);   // core-only

        float e0A = lplb[(size_t)(Tn - 1) * LPS + c0];      // row for step T
        float e1A = lplb[(size_t)(Tn - 1) * LPS + c0 + 1];
        float e0B = e0A, e1B = e1A;                          // row for step T-1
        int T = Tn - 1;
        for (int win = 0; win < 134; ++win) {
            LBAR();
            if (wid < 3 && lane < 24)            // halo <- neighbor core
                buf[0][wid][102 + lane] = buf[0][wid + 1][lane];
            LBAR();
            for (int j = 0; j < KW; ++j) {
                if (T < 0) break;                // block-uniform
                const int it = (Tn - 1 - T) & 1;
                const float* cur = &buf[it][wid][0];
                float* nxt = &buf[it ^ 1][wid][0];
                int nrow = T - 1; if (nrow < 0) nrow = 0;
                float n0 = lplb[(size_t)nrow * LPS + c0];
                float n1 = lplb[(size_t)nrow * LPS + c0 + 1];
                int ebrow = T + 1; if (ebrow > Tn - 1) ebrow = Tn - 1;
                float eb = ebs[ebrow];
                if (act) {
                    float cc0 = cur[2 * lane];
                    float cc1 = cur[2 * lane + 1];
                    float cc2 = cur[2 * lane + 2];
                    float cc3 = cur[2 * lane + 3];
                    float g0e = eb + cc0;
                    float g1e = e0A + cc1;
                    float nv0 = lse2f(g0e, g1e);
                    float g0o = e0A + cc1;
                    float g1o = eb + cc2;
                    float g2o = a2 ? (e1A + cc3) : NEGINF;
                    float mh = fmaxf(g1o, g2o);
                    float h = NEGINF;
                    if (!isinf(mh))
                        h = mh + __logf(__expf(g1o - mh) + __expf(g2o - mh));
                    float nv1 = v1 ? lse3f(g0o, g1o, g2o) : NEGINF;
                    if (T == hlen - 1) {
                        nv0 = (g0 == 2 * olen || g0 == 2 * olen - 1) ? 0.f : NEGINF;
                        nv1 = (g1 == 2 * olen || g1 == 2 * olen - 1) ? 0.f : NEGINF;
                    }
                    nxt[2 * lane]     = v0 ? nv0 : NEGINF;
                    nxt[2 * lane + 1] = v1 ? nv1 : NEGINF;
                    if (isstar) {
                        float bp;
                        if (T >= hlen)          bp = NEGINF;
                        else if (T == hlen - 1) bp = 0.f;          // u == olen-1
                        else if (isinf(g0o))    bp = h;
                        else if (isinf(h))      bp = LSE_SUB_CONST_F;
                        else {
                            float sumlog = h - g0o;
                            int k2 = (int)((__float_as_uint(fabsf(g0o)) >> 23) & 0xFF) - 127 - 53;
                            if (k2 < -53) k2 = -53;
                            bp = (sumlog > 709.7827f || sumlog < 0.69314718f * (float)k2)
                                 ? LSE_SUB_CONST_F : h;
                        }
                        bs[T] = bp;
                    }
                }
                LGKM_FENCE();
                e0A = e0B; e1A = e1B; e0B = n0; e1B = n1;
                --T;
            }
        }
    }
}

// --------------------- K3: loss at u* only --------------------------------
#define TCH 8
#define TPC (Tn / TCH)

__global__ __launch_bounds__(64)
void loss_kernel(const int* __restrict__ hlens, const int* __restrict__ ys,
                 const float* __restrict__ ast, const float* __restrict__ bst,
                 float* __restrict__ lossb)
{
    const int b = blockIdx.x, tid = threadIdx.x;
    __shared__ float sm[TCH], ss[TCH];
    __shared__ int sh_olen;
    if (tid == 0) {
        int o = 0;
        for (int u = 0; u < Un; u++) if (ys[b * Un + u] >= 0) o++;
        sh_olen = o;
    }
    __syncthreads();
    const int hlen = hlens[b];
    const float risk_c = 0.1f / (float)hlen;
    if (tid < TCH) {
        float m = NEGINF, s = 0.f;
        const float* as = ast + (size_t)b * Tn;
        const float* bs = bst + (size_t)b * Tn;
        const int t0 = tid * TPC, t1 = t0 + TPC;
        for (int t = t0; t < t1; ++t) {
            float v = as[t] + bs[t] + (float)(t + 1) * risk_c;
            if (!isinf(v)) lse_merge_v(m, s, v);
        }
        sm[tid] = m; ss[tid] = s;
    }
    __syncthreads();
    if (tid == 0) {
        float M = NEGINF, S = 0.f;
        #pragma unroll
        for (int c = 0; c < TCH; ++c) lse_merge_ms(M, S, sm[c], ss[c]);
        float lf = (S == 0.f) ? NEGINF : M + __logf(S);
        if (hlen < sh_olen) lf = 0.f;
        lossb[b] = lf;
    }
}

// ---------------------------------------------------------------- K4 ------
__global__ void finalize_kernel(const float* __restrict__ lossb, float* __restrict__ out) {
    if (threadIdx.x == 0 && blockIdx.x == 0) {
        float ssum = 0.f;
        for (int i = 0; i < Bn; i++) ssum += lossb[i];
        out[0] = -ssum / (float)Bn;
    }
}

// ------------------------------------------------------------- launch -----
extern "C" void kernel_launch(void* const* d_in, const int* in_sizes, int n_in,
                              void* d_out, int out_size, void* d_ws, size_t ws_size,
                              hipStream_t stream) {
    const float* hs    = (const float*)d_in[0];
    const float* W     = (const float*)d_in[1];
    const float* bias  = (const float*)d_in[2];
    const int*   hlens = (const int*)d_in[3];
    const int*   ys    = (const int*)d_in[4];
    float* out = (float*)d_out;

    // ---- workspace (~63 MB) ----
    char* p = (char*)d_ws;
    float* lpl    = (float*)p;  p += (size_t)25601 * LPS * 4;         // 26.2 MB
    float* lpbk   = (float*)p;  p += (size_t)25600 * 4;               // 0.10 MB
    unsigned short* hsb = (unsigned short*)p; p += (size_t)25600 * NE * 2;    // 26.2 MB
    unsigned short* Wb  = (unsigned short*)p; p += (size_t)OD * NE * 2;       // 2.1 MB
    unsigned short* Wgb = (unsigned short*)p; p += (size_t)Bn * NGC * NE * 2; // 4.2 MB
    float* Pm    = (float*)p;   p += (size_t)16 * 25600 * 4;          // 1.64 MB
    float* Ps    = (float*)p;   p += (size_t)16 * 25600 * 4;          // 1.64 MB
    float* lse   = (float*)p;   p += (size_t)25600 * 4;               // 0.10 MB
    float* biasg = (float*)p;   p += (size_t)Bn * NGC * 4;            // 16 KB
    float* ast   = (float*)p;   p += (size_t)Bn * Tn * 4;             // 0.10 MB
    float* bst   = (float*)p;   p += (size_t)Bn * Tn * 4;             // 0.10 MB
    float* lossb = (float*)p;   p += 256;

    hipLaunchKernelGGL(cast_hs_kernel, dim3(6400), dim3(256), 0, stream,
                       hs, hsb, 25600 * NE / 8);
    hipLaunchKernelGGL(cast_hs_kernel, dim3(512), dim3(256), 0, stream,
                       W, Wb, OD * NE / 8);
    hipLaunchKernelGGL(gather_kernel, dim3(Bn, NGC), dim3(64), 0, stream,
                       W, bias, ys, Wgb, biasg);
    hipLaunchKernelGGL(gemm_main_kernel, dim3(200, 16), dim3(256), 0, stream,
                       hsb, Wb, bias, Pm, Ps);
    hipLaunchKernelGGL(lse_reduce_kernel, dim3(100), dim3(256), 0, stream,
                       Pm, Ps, lse);
    hipLaunchKernelGGL(gemm_label_kernel, dim3(400, 2), dim3(256), 0, stream,
                       hsb, Wgb, biasg, lse, lpl, lpbk);
    hipLaunchKernelGGL(scan_kernel, dim3(2 * Bn), dim3(256), 0, stream,
                       lpl, lpbk, hlens, ys, ast, bst);
    hipLaunchKernelGGL(loss_kernel, dim3(Bn), dim3(64), 0, stream,
                       hlens, ys, ast, bst, lossb);
    hipLaunchKernelGGL(finalize_kernel, dim3(1), dim3(64), 0, stream, lossb, out);
}

// Round 11
// 1207.760 us; speedup vs baseline: 1.8018x; 1.0167x over previous
//
#include <hip/hip_runtime.h>
#include <math.h>

// BayesianCTC on MI355X — round 22.
// R21 post-mortem: removing 1335/1600 barriers changed NOTHING (899 vs 895us)
// -> s_barrier was never the cost. Last suspect standing, now consistent with
// every counter: the per-step global emission load is IN the chain. VGPR=16
// cannot hold the rotating prefetch; allocator reuses registers -> per-step
// s_waitcnt vmcnt(<=1) waits on a ~1-step-old load -> ~800cy exposed L3
// latency/step (130 ds + 200 arith + 150 fence + 800 load = 1280 ~ measured
// 1350 — first model that closes).
// R22: emissions NEVER touch VGPRs. __builtin_amdgcn_global_load_lds DMA:
// one row = 1024B = one dwordx4 wave-instruction (LPS=256 by design).
// Window = 16 steps, double-buffered em[2][16][256] (32KB): issue 16 rows
// for window k+1 at start of window k (4 instr/wave, no registers, no
// waits); steps read emissions from LDS; boundary = vmcnt(0) (a full window
// ~8000cy to land) + barrier. R18 math byte-identical (staged rows/cols =
// exact values R18 loaded, incl. zero-filled cols) -> absmax 0.0 expected.

#define Bn    16
#define Tn    1600
#define NE    512
#define OD    2048
#define Un    200
#define Sn    401
#define NLAB  201
#define NGC   256
#define LPS   256              // lpl row stride (floats) = 1024 B = 1 dwordx4/wave
#define WS    16               // steps per DMA window
#define NW    100              // windows

#define NEGINF (-INFINITY)
#define LSE_SUB_CONST_F (-2000.4586715f)        // -2001 + log(e-1)

typedef short bf8_t  __attribute__((ext_vector_type(8)));
typedef float f32x4  __attribute__((ext_vector_type(4)));

__device__ __forceinline__ unsigned short f2bf(float x) {
    unsigned int u = __float_as_uint(x);
    unsigned int r = (u + 0x7FFFu + ((u >> 16) & 1u)) >> 16;  // RNE
    return (unsigned short)r;
}
__device__ __forceinline__ void lse_merge_v(float& M, float& S, float v) {
    if (v > M) { S = S * __expf(M - v) + 1.f; M = v; }
    else       { S += __expf(v - M); }
}
__device__ __forceinline__ void lse_merge_ms(float& M, float& S, float m2, float s2) {
    if (s2 > 0.f) {
        if (m2 > M) { S = S * __expf(M - m2) + s2; M = m2; }
        else        { S += s2 * __expf(m2 - M); }
    }
}

// ------------------------------------------------------------ casts -------
__global__ __launch_bounds__(256)
void cast_hs_kernel(const float* __restrict__ src, unsigned short* __restrict__ dst, int n8) {
    int i = blockIdx.x * 256 + threadIdx.x;
    if (i >= n8) return;
    const float4* s4 = (const float4*)(src + (size_t)i * 8);
    float4 a = s4[0], b = s4[1];
    uint4 o;
    o.x = f2bf(a.x) | ((unsigned)f2bf(a.y) << 16);
    o.y = f2bf(a.z) | ((unsigned)f2bf(a.w) << 16);
    o.z = f2bf(b.x) | ((unsigned)f2bf(b.y) << 16);
    o.w = f2bf(b.z) | ((unsigned)f2bf(b.w) << 16);
    *(uint4*)(dst + (size_t)i * 8) = o;
}

// --------------------------------------------------------- gather Wg ------
__global__ __launch_bounds__(64)
void gather_kernel(const float* __restrict__ W, const float* __restrict__ bias,
                   const int* __restrict__ ys, unsigned short* __restrict__ Wgb,
                   float* __restrict__ biasg)
{
    const int b = blockIdx.x, j = blockIdx.y, tid = threadIdx.x;
    int col = -1;
    if (j == 0) col = 0;
    else if (j <= Un) { int y = ys[b * Un + j - 1]; col = (y < 0) ? 0 : y; }
    unsigned short* dst = Wgb + ((size_t)b * NGC + j) * NE;
    if (col >= 0) {
        const float* srcc = W + (size_t)col * NE;
        #pragma unroll
        for (int it = 0; it < 8; ++it) dst[tid + it * 64] = f2bf(srcc[tid + it * 64]);
    } else {
        #pragma unroll
        for (int it = 0; it < 8; ++it) dst[tid + it * 64] = 0;
    }
    if (tid == 0) biasg[b * NGC + j] = (col >= 0) ? bias[col] : 0.f;
}

// ------------------------------------------------------- main MFMA GEMM ---
#define KCH  64
#define ASTR 72

__global__ __launch_bounds__(256, 2)
void gemm_main_kernel(const unsigned short* __restrict__ hsb,
                      const unsigned short* __restrict__ Wb,
                      const float* __restrict__ bias,
                      float* __restrict__ Pm, float* __restrict__ Ps)
{
    __shared__ union {
        struct { unsigned short A[128 * ASTR]; unsigned short B[128 * ASTR]; } t;
        struct { float m[128 * 33]; float s[128 * 33]; } r;
    } sh;
    const int tid  = threadIdx.x;
    const int lane = tid & 63, w = tid >> 6;
    const int mw = w & 1, nw = w >> 1;
    const int quad = lane >> 4, lc = lane & 15;
    const int row0 = blockIdx.x * 128;
    const int c0   = blockIdx.y * 128;

    f32x4 acc[4][4];
    #pragma unroll
    for (int mi = 0; mi < 4; ++mi)
        #pragma unroll
        for (int ni = 0; ni < 4; ++ni) acc[mi][ni] = (f32x4)0.f;

    for (int kc = 0; kc < NE / KCH; ++kc) {
        __syncthreads();
        #pragma unroll
        for (int i = 0; i < 4; ++i) {
            int idx = tid + i * 256;
            int r = idx >> 3, c8 = idx & 7;
            *(uint4*)&sh.t.A[r * ASTR + c8 * 8] =
                *(const uint4*)&hsb[(size_t)(row0 + r) * NE + kc * KCH + c8 * 8];
            *(uint4*)&sh.t.B[r * ASTR + c8 * 8] =
                *(const uint4*)&Wb[(size_t)(c0 + r) * NE + kc * KCH + c8 * 8];
        }
        __syncthreads();
        #pragma unroll
        for (int ks = 0; ks < 2; ++ks) {
            bf8_t af[4], bg[4];
            #pragma unroll
            for (int mi = 0; mi < 4; ++mi)
                af[mi] = *(const bf8_t*)&sh.t.A[(mw * 64 + mi * 16 + lc) * ASTR + ks * 32 + quad * 8];
            #pragma unroll
            for (int ni = 0; ni < 4; ++ni)
                bg[ni] = *(const bf8_t*)&sh.t.B[(nw * 64 + ni * 16 + lc) * ASTR + ks * 32 + quad * 8];
            #pragma unroll
            for (int mi = 0; mi < 4; ++mi)
                #pragma unroll
                for (int ni = 0; ni < 4; ++ni)
                    acc[mi][ni] = __builtin_amdgcn_mfma_f32_16x16x32_bf16(af[mi], bg[ni], acc[mi][ni], 0, 0, 0);
        }
    }
    __syncthreads();
    float bcol[4];
    #pragma unroll
    for (int ni = 0; ni < 4; ++ni) bcol[ni] = bias[c0 + nw * 64 + ni * 16 + lc];
    #pragma unroll
    for (int mi = 0; mi < 4; ++mi)
        #pragma unroll
        for (int r = 0; r < 4; ++r) {
            float M = NEGINF, S = 0.f;
            #pragma unroll
            for (int ni = 0; ni < 4; ++ni) lse_merge_v(M, S, acc[mi][ni][r] + bcol[ni]);
            int rl = mw * 64 + mi * 16 + quad * 4 + r;
            sh.r.m[rl * 33 + nw * 16 + lc] = M;
            sh.r.s[rl * 33 + nw * 16 + lc] = S;
        }
    __syncthreads();
    if (tid < 128) {
        float M = NEGINF, S = 0.f;
        #pragma unroll 4
        for (int j = 0; j < 32; ++j) lse_merge_ms(M, S, sh.r.m[tid * 33 + j], sh.r.s[tid * 33 + j]);
        Pm[(size_t)blockIdx.y * 25600 + row0 + tid] = M;
        Ps[(size_t)blockIdx.y * 25600 + row0 + tid] = S;
    }
}

// ------------------------------------------------------------ lse reduce --
__global__ __launch_bounds__(256)
void lse_reduce_kernel(const float* __restrict__ Pm, const float* __restrict__ Ps,
                       float* __restrict__ lse)
{
    int row = blockIdx.x * 256 + threadIdx.x;
    float M = NEGINF, S = 0.f;
    #pragma unroll 4
    for (int nt = 0; nt < 16; ++nt)
        lse_merge_ms(M, S, Pm[(size_t)nt * 25600 + row], Ps[(size_t)nt * 25600 + row]);
    lse[row] = M + logf(S);
}

// ------------------------------------------------------- label MFMA GEMM --
// lpbk[row] = blank col; lpl[row][u] (stride LPS=256): u=col-1 for col 1..200,
// cols 201..255 zero-filled (staged/read unconditionally downstream).
__global__ __launch_bounds__(256, 2)
void gemm_label_kernel(const unsigned short* __restrict__ hsb,
                       const unsigned short* __restrict__ Wgb,
                       const float* __restrict__ biasg, const float* __restrict__ lse,
                       float* __restrict__ lpl, float* __restrict__ lpbk)
{
    __shared__ unsigned short shA[64 * ASTR];
    __shared__ unsigned short shB[128 * ASTR];
    const int tid  = threadIdx.x;
    const int lane = tid & 63, w = tid >> 6;
    const int mw = w & 1, nw = w >> 1;
    const int quad = lane >> 4, lc = lane & 15;
    const int b  = blockIdx.x / 25, mt = blockIdx.x % 25;
    const int r0 = b * Tn + mt * 64;
    const int c0 = blockIdx.y * 128;

    f32x4 acc[2][4];
    #pragma unroll
    for (int mi = 0; mi < 2; ++mi)
        #pragma unroll
        for (int ni = 0; ni < 4; ++ni) acc[mi][ni] = (f32x4)0.f;

    const unsigned short* Wgbb = Wgb + (size_t)b * NGC * NE;
    for (int kc = 0; kc < NE / KCH; ++kc) {
        __syncthreads();
        #pragma unroll
        for (int i = 0; i < 2; ++i) {
            int idx = tid + i * 256;
            int r = idx >> 3, c8 = idx & 7;
            *(uint4*)&shA[r * ASTR + c8 * 8] =
                *(const uint4*)&hsb[(size_t)(r0 + r) * NE + kc * KCH + c8 * 8];
        }
        #pragma unroll
        for (int i = 0; i < 4; ++i) {
            int idx = tid + i * 256;
            int r = idx >> 3, c8 = idx & 7;
            *(uint4*)&shB[r * ASTR + c8 * 8] =
                *(const uint4*)&Wgbb[(size_t)(c0 + r) * NE + kc * KCH + c8 * 8];
        }
        __syncthreads();
        #pragma unroll
        for (int ks = 0; ks < 2; ++ks) {
            bf8_t af[2], bg[4];
            #pragma unroll
            for (int mi = 0; mi < 2; ++mi)
                af[mi] = *(const bf8_t*)&shA[(mw * 32 + mi * 16 + lc) * ASTR + ks * 32 + quad * 8];
            #pragma unroll
            for (int ni = 0; ni < 4; ++ni)
                bg[ni] = *(const bf8_t*)&shB[(nw * 64 + ni * 16 + lc) * ASTR + ks * 32 + quad * 8];
            #pragma unroll
            for (int mi = 0; mi < 2; ++mi)
                #pragma unroll
                for (int ni = 0; ni < 4; ++ni)
                    acc[mi][ni] = __builtin_amdgcn_mfma_f32_16x16x32_bf16(af[mi], bg[ni], acc[mi][ni], 0, 0, 0);
        }
    }
    #pragma unroll
    for (int mi = 0; mi < 2; ++mi)
        #pragma unroll
        for (int r = 0; r < 4; ++r) {
            int row = r0 + mw * 32 + mi * 16 + quad * 4 + r;
            float lsv = lse[row];
            #pragma unroll
            for (int ni = 0; ni < 4; ++ni) {
                int col = c0 + nw * 64 + ni * 16 + lc;
                float v = acc[mi][ni][r] + biasg[b * NGC + col] - lsv;
                if (col == 0)          lpbk[row] = v;
                else if (col < NLAB)   lpl[(size_t)row * LPS + (col - 1)] = v;
                else                   lpl[(size_t)row * LPS + (col - 1)] = 0.f;
            }
        }
}

// ------- K2: LDS ping-pong scan + DMA-windowed emissions (R18 math) -------
#define IDX(s) ((s) + 2)          // buf index for state s; pads [0,1],[403..407]

__device__ __forceinline__ float lse2f(float a, float b) {
    float mx = fmaxf(a, b);
    if (isinf(mx)) return NEGINF;
    return mx + __logf(__expf(a - mx) + __expf(b - mx));
}
__device__ __forceinline__ float lse3f(float v0, float v1, float v2) {
    float mx = fmaxf(v0, fmaxf(v1, v2));
    if (isinf(mx)) return NEGINF;
    return mx + __logf(__expf(v0 - mx) + __expf(v1 - mx) + __expf(v2 - mx));
}

// LDS-only barrier: ds ops ordered, global/DMA loads stay in flight.
#define STEP_BAR() do { \
    asm volatile("s_waitcnt lgkmcnt(0)" ::: "memory"); \
    __builtin_amdgcn_s_barrier(); \
    __builtin_amdgcn_sched_barrier(0); \
} while (0)
// window boundary: DMA for next window landed + visible to all waves
#define WIN_BAR() do { \
    asm volatile("s_waitcnt vmcnt(0) lgkmcnt(0)" ::: "memory"); \
    __builtin_amdgcn_s_barrier(); \
    __builtin_amdgcn_sched_barrier(0); \
} while (0)

__global__ __launch_bounds__(256)
void scan_kernel(const float* __restrict__ lpl, const float* __restrict__ lpbk,
                 const int* __restrict__ hlens, const int* __restrict__ ys,
                 float* __restrict__ ast, float* __restrict__ bst)
{
    __shared__ float buf[2][408];
    __shared__ float ebs[Tn];            // blank emissions (6.4 KB)
    __shared__ float em[2][WS][LPS];     // DMA-staged emission rows (32 KB)
    __shared__ int   sh_olen, sh_hlen;

    const int b    = blockIdx.x & (Bn - 1);
    const int role = blockIdx.x >> 4;
    const int tid  = threadIdx.x;        // thread i owns states 2i, 2i+1
    const int wid  = tid >> 6, lane = tid & 63;

    if (tid == 0) {
        int o = 0;
        for (int u = 0; u < Un; u++) if (ys[b * Un + u] >= 0) o++;
        sh_olen = o;
        sh_hlen = hlens[b];
    }
    for (int idx = tid; idx < 408; idx += 256) {
        buf[0][idx] = NEGINF;
        buf[1][idx] = NEGINF;
    }
    const float* lpbb = lpbk + (size_t)b * Tn;
    for (int i = tid; i < Tn; i += 256) ebs[i] = lpbb[i];

    // allow flags in registers (loop-invariant)
    bool a1allow = false;                // allow for odd state s1 (u = tid)
    if (tid >= 1 && tid < Un) {
        int y0 = ys[b * Un + tid - 1]; if (y0 < 0) y0 = 0;
        int y1 = ys[b * Un + tid];     if (y1 < 0) y1 = 0;
        a1allow = (y0 != y1);
    }
    bool a2allow = false;                // allow for odd state s1+2 (u = tid+1)
    if (tid + 1 >= 1 && tid + 1 < Un) {
        int y0 = ys[b * Un + tid];     if (y0 < 0) y0 = 0;
        int y1 = ys[b * Un + tid + 1]; if (y1 < 0) y1 = 0;
        a2allow = (y0 != y1);
    }

    const float* lplb = lpl + (size_t)b * Tn * LPS;
    const int s0 = 2 * tid, s1 = 2 * tid + 1;
    const bool v0ok = (s0 < Sn);         // tid <= 200
    const bool v1ok = (s1 < Sn);         // tid < 200

    // ---- DMA: stage the 16 emission rows of window k into em[bufi] ----
    // exec index j = WS*k + i; row: alpha r = min(j+1,1599); beta
    // r = min(1600-j,1599). Wave w stages i = 4w..4w+3, one dwordx4 each:
    // lane l deposits floats 4l..4l+3 of the row (LPS=256 = 1024B = 1 instr).
    auto dma_window = [&](int k, int bufi) {
        #pragma unroll
        for (int m = 0; m < 4; ++m) {
            int i = 4 * wid + m;
            int j = WS * k + i;
            int r = role ? (1600 - j) : (j + 1);
            if (r > Tn - 1) r = Tn - 1;
            __builtin_amdgcn_global_load_lds(
                (const __attribute__((address_space(1))) unsigned int*)
                    &lplb[(size_t)r * LPS + 4 * lane],
                (__attribute__((address_space(3))) unsigned int*)
                    &em[bufi][i][0],
                16, 0, 0);
        }
    };

    dma_window(0, 0);                    // prologue: stage window 0
    __syncthreads();                     // also covers buf/ebs init

    const int  olen = sh_olen, hlen = sh_hlen;
    const int  ustar = olen - 1;

    if (role == 0) {
        // ------------------------- alpha -------------------------
        float* as = ast + (size_t)b * Tn;
        if (tid == 0) { buf[0][IDX(0)] = ebs[0]; buf[0][IDX(1)] = lplb[0]; }
        if (tid == ustar) as[0] = (tid == 0) ? lplb[0] : NEGINF;
        WIN_BAR();                        // window-0 DMA landed + init visible

        for (int k = 0; k < NW; ++k) {
            const int cb = k & 1;
            if (k + 1 < NW) dma_window(k + 1, cb ^ 1);
            for (int i = 0; i < WS; ++i) {
                const int t = WS * k + i + 1;
                if (t < Tn) {             // block-uniform
                    const float* cur = buf[(t - 1) & 1];
                    float* nxt = buf[t & 1];
                    if (v0ok) {
                        float eo = em[cb][i][tid];
                        float c1 = cur[IDX(s0) - 1];
                        float c2 = cur[IDX(s0)], c3 = cur[IDX(s1)];
                        float nv0 = lse2f(c2, c1) + ebs[t];
                        nxt[IDX(s0)] = nv0;
                        if (v1ok) {
                            float a1v2 = a1allow ? c1 : NEGINF;
                            float nv1 = lse3f(c3, c2, a1v2) + eo;
                            nxt[IDX(s1)] = nv1;
                            if (tid == ustar) as[t] = nv1;
                        }
                    }
                    STEP_BAR();
                }
            }
            WIN_BAR();                    // next window's DMA landed
        }
    } else {
        // ------------------ beta + in-scan beta_prime ------------------
        float* bs = bst + (size_t)b * Tn;
        WIN_BAR();                        // window-0 DMA landed + init visible

        for (int k = 0; k < NW; ++k) {
            const int cb = k & 1;
            if (k + 1 < NW) dma_window(k + 1, cb ^ 1);
            for (int i = 0; i < WS; ++i) {
                const int j = WS * k + i;
                const int T = Tn - 1 - j;
                const int it = j & 1;
                const float* cur = buf[it];
                float* nxt = buf[it ^ 1];
                float eb = ebs[(T + 1 > Tn - 1) ? (Tn - 1) : (T + 1)];
                if (v0ok) {
                    float e0 = em[cb][i][tid];
                    float e1 = em[cb][i][tid + 1];   // tid<=200 -> col<=201 ok
                    float c0 = cur[IDX(s0)],     c1 = cur[IDX(s0) + 1];
                    float c2 = cur[IDX(s0) + 2], c3 = cur[IDX(s0) + 3];
                    float g0e = eb + c0;
                    float g1e = e0 + c1;
                    float nv0 = lse2f(g0e, g1e);
                    float g0o = e0 + c1;
                    float g1o = eb + c2;
                    float g2o = a2allow ? (e1 + c3) : NEGINF;
                    float mh = fmaxf(g1o, g2o);
                    float h = NEGINF;
                    if (!isinf(mh))
                        h = mh + __logf(__expf(g1o - mh) + __expf(g2o - mh));
                    float nv1 = v1ok ? lse3f(g0o, g1o, g2o) : NEGINF;
                    if (T == hlen - 1) {
                        nv0 = (s0 == 2 * olen || s0 == 2 * olen - 1) ? 0.f : NEGINF;
                        nv1 = (s1 == 2 * olen || s1 == 2 * olen - 1) ? 0.f : NEGINF;
                    }
                    nxt[IDX(s0)] = nv0;
                    if (v1ok) {
                        nxt[IDX(s1)] = nv1;
                        if (tid == ustar) {
                            float bp;
                            if (T >= hlen)          bp = NEGINF;
                            else if (T == hlen - 1) bp = 0.f;     // tid==olen-1
                            else if (isinf(g0o))    bp = h;
                            else if (isinf(h))      bp = LSE_SUB_CONST_F;
                            else {
                                float sumlog = h - g0o;
                                int kk = (int)((__float_as_uint(fabsf(g0o)) >> 23) & 0xFF) - 127 - 53;
                                if (kk < -53) kk = -53;
                                bp = (sumlog > 709.7827f || sumlog < 0.69314718f * (float)kk)
                                     ? LSE_SUB_CONST_F : h;
                            }
                            bs[T] = bp;
                        }
                    }
                }
                STEP_BAR();
            }
            WIN_BAR();                    // next window's DMA landed
        }
    }
}

// --------------------- K3: loss at u* only --------------------------------
#define TCH 8
#define TPC (Tn / TCH)

__global__ __launch_bounds__(64)
void loss_kernel(const int* __restrict__ hlens, const int* __restrict__ ys,
                 const float* __restrict__ ast, const float* __restrict__ bst,
                 float* __restrict__ lossb)
{
    const int b = blockIdx.x, tid = threadIdx.x;
    __shared__ float sm[TCH], ss[TCH];
    __shared__ int sh_olen;
    if (tid == 0) {
        int o = 0;
        for (int u = 0; u < Un; u++) if (ys[b * Un + u] >= 0) o++;
        sh_olen = o;
    }
    __syncthreads();
    const int hlen = hlens[b];
    const float risk_c = 0.1f / (float)hlen;
    if (tid < TCH) {
        float m = NEGINF, s = 0.f;
        const float* as = ast + (size_t)b * Tn;
        const float* bs = bst + (size_t)b * Tn;
        const int t0 = tid * TPC, t1 = t0 + TPC;
        for (int t = t0; t < t1; ++t) {
            float v = as[t] + bs[t] + (float)(t + 1) * risk_c;
            if (!isinf(v)) lse_merge_v(m, s, v);
        }
        sm[tid] = m; ss[tid] = s;
    }
    __syncthreads();
    if (tid == 0) {
        float M = NEGINF, S = 0.f;
        #pragma unroll
        for (int c = 0; c < TCH; ++c) lse_merge_ms(M, S, sm[c], ss[c]);
        float lf = (S == 0.f) ? NEGINF : M + __logf(S);
        if (hlen < sh_olen) lf = 0.f;
        lossb[b] = lf;
    }
}

// ---------------------------------------------------------------- K4 ------
__global__ void finalize_kernel(const float* __restrict__ lossb, float* __restrict__ out) {
    if (threadIdx.x == 0 && blockIdx.x == 0) {
        float ssum = 0.f;
        for (int i = 0; i < Bn; i++) ssum += lossb[i];
        out[0] = -ssum / (float)Bn;
    }
}

// ------------------------------------------------------------- launch -----
extern "C" void kernel_launch(void* const* d_in, const int* in_sizes, int n_in,
                              void* d_out, int out_size, void* d_ws, size_t ws_size,
                              hipStream_t stream) {
    const float* hs    = (const float*)d_in[0];
    const float* W     = (const float*)d_in[1];
    const float* bias  = (const float*)d_in[2];
    const int*   hlens = (const int*)d_in[3];
    const int*   ys    = (const int*)d_in[4];
    float* out = (float*)d_out;

    // ---- workspace (~63 MB) ----
    char* p = (char*)d_ws;
    float* lpl    = (float*)p;  p += (size_t)25601 * LPS * 4;         // 26.2 MB
    float* lpbk   = (float*)p;  p += (size_t)25600 * 4;               // 0.10 MB
    unsigned short* hsb = (unsigned short*)p; p += (size_t)25600 * NE * 2;    // 26.2 MB
    unsigned short* Wb  = (unsigned short*)p; p += (size_t)OD * NE * 2;       // 2.1 MB
    unsigned short* Wgb = (unsigned short*)p; p += (size_t)Bn * NGC * NE * 2; // 4.2 MB
    float* Pm    = (float*)p;   p += (size_t)16 * 25600 * 4;          // 1.64 MB
    float* Ps    = (float*)p;   p += (size_t)16 * 25600 * 4;          // 1.64 MB
    float* lse   = (float*)p;   p += (size_t)25600 * 4;               // 0.10 MB
    float* biasg = (float*)p;   p += (size_t)Bn * NGC * 4;            // 16 KB
    float* ast   = (float*)p;   p += (size_t)Bn * Tn * 4;             // 0.10 MB
    float* bst   = (float*)p;   p += (size_t)Bn * Tn * 4;             // 0.10 MB
    float* lossb = (float*)p;   p += 256;

    hipLaunchKernelGGL(cast_hs_kernel, dim3(6400), dim3(256), 0, stream,
                       hs, hsb, 25600 * NE / 8);
    hipLaunchKernelGGL(cast_hs_kernel, dim3(512), dim3(256), 0, stream,
                       W, Wb, OD * NE / 8);
    hipLaunchKernelGGL(gather_kernel, dim3(Bn, NGC), dim3(64), 0, stream,
                       W, bias, ys, Wgb, biasg);
    hipLaunchKernelGGL(gemm_main_kernel, dim3(200, 16), dim3(256), 0, stream,
                       hsb, Wb, bias, Pm, Ps);
    hipLaunchKernelGGL(lse_reduce_kernel, dim3(100), dim3(256), 0, stream,
                       Pm, Ps, lse);
    hipLaunchKernelGGL(gemm_label_kernel, dim3(400, 2), dim3(256), 0, stream,
                       hsb, Wgb, biasg, lse, lpl, lpbk);
    hipLaunchKernelGGL(scan_kernel, dim3(2 * Bn), dim3(256), 0, stream,
                       lpl, lpbk, hlens, ys, ast, bst);
    hipLaunchKernelGGL(loss_kernel, dim3(Bn), dim3(64), 0, stream,
                       hlens, ys, ast, bst, lossb);
    hipLaunchKernelGGL(finalize_kernel, dim3(1), dim3(64), 0, stream, lossb, out);
}